// Round 6
// baseline (1458.837 us; speedup 1.0000x reference)
//
#include <hip/hip_runtime.h>
#include <hip/hip_bf16.h>

// Shapes: B=512, S=128, D=128, HS=256, 4HS=1024, O=1.
// k_seq v6 = r2/r5 structure (32 blocks, no exchange) with latency fixes:
//   - raw s_barrier (lgkmcnt-only): outh store acks no longer drained per step
//   - Gx software-pipelined one full step ahead (HBM latency off critical path)
//   - U kc5,6 issued at step top, kc7 mid-phase (deep L2 prefetch)
//   - U kc0-2 AGPR-pinned, kc3-4 LDS-resident (unchanged from r5)

using bf16x8 = __attribute__((ext_vector_type(8))) short;
using f32x4  = __attribute__((ext_vector_type(4))) float;

#define DEV static __device__ __forceinline__

DEV unsigned short f2bf(float x) {
    unsigned u = __float_as_uint(x);
    u += 0x7fffu + ((u >> 16) & 1u);          // round-to-nearest-even
    return (unsigned short)(u >> 16);
}
DEV float bf2f(unsigned short s) { return __uint_as_float(((unsigned)s) << 16); }
DEV float sigm(float x) { return 1.0f / (1.0f + __expf(-x)); }
DEV float tanh_f(float x) { float e = __expf(2.0f * x); return 1.0f - 2.0f / (e + 1.0f); }
DEV f32x4 mfma16(bf16x8 a, bf16x8 b, f32x4 c) {
    return __builtin_amdgcn_mfma_f32_16x16x32_bf16(a, b, c, 0, 0, 0);
}

// stage rows x 128 bf16 (row stride 128) into LDS with padded stride 136
DEV void stage128(const unsigned short* __restrict__ src, unsigned short* dst, int rows, int tid) {
    int chunks = rows * 16;
    for (int i = tid; i < chunks; i += 256) {
        int r = i >> 4, c = (i & 15) << 3;
        *(bf16x8*)(dst + r * 136 + c) = *(const bf16x8*)(src + r * 128 + c);
    }
}

// ---------------- prep kernels ----------------
__global__ void k_prepw(const float* __restrict__ Wa, const float* __restrict__ Va,
                        const float* __restrict__ W, const float* __restrict__ U,
                        unsigned short* __restrict__ WaT, unsigned short* __restrict__ VaT,
                        unsigned short* __restrict__ WT, unsigned short* __restrict__ Upk) {
    int idx = blockIdx.x * 256 + threadIdx.x;
    if (idx < 16384) {
        int n = idx >> 7, k = idx & 127;
        WaT[idx] = f2bf(Wa[k * 128 + n]);
    } else if (idx < 32768) {
        int i = idx - 16384;
        int n = i >> 7, k = i & 127;
        VaT[i] = f2bf(Va[k * 128 + n]);
    } else if (idx < 163840) {
        int i = idx - 32768;
        int n = i >> 7, k = i & 127;
        WT[i] = f2bf(W[k * 1024 + n]);
    } else if (idx < 425984) {
        int i = idx - 163840;   // layout: ((((w*8+kc)*8+tt)*64+l)*8+j
        int j = i & 7, ll = (i >> 3) & 63, tt = (i >> 9) & 7, kc = (i >> 12) & 7, w = i >> 15;
        int k = kc * 32 + (ll >> 4) * 8 + j;
        int n = (tt >> 1) * 256 + w * 32 + (tt & 1) * 16 + (ll & 15);
        Upk[i] = f2bf(U[k * 1024 + n]);
    }
}

__global__ void k_preph(const float* __restrict__ H, unsigned short* __restrict__ Hbf,
                        unsigned short* __restrict__ HT) {
    for (size_t idx = (size_t)blockIdx.x * 256 + threadIdx.x; idx < 16777216u;
         idx += (size_t)gridDim.x * 256) {
        if (idx < 8388608u) {
            Hbf[idx] = f2bf(H[idx]);
        } else {
            size_t i = idx - 8388608u;
            int b = (int)(i >> 14);
            int rem = (int)(i & 16383);
            int d = rem >> 7, s = rem & 127;
            HT[i] = f2bf(H[((size_t)b * 128 + s) * 128 + d]);
        }
    }
}

// ---------------- T1 = tanh(H @ Wa + ba) ----------------
__global__ __launch_bounds__(256) void k_att1(const unsigned short* __restrict__ Hbf,
                                              const unsigned short* __restrict__ WaT,
                                              const float* __restrict__ ba,
                                              unsigned short* __restrict__ T1) {
    __shared__ unsigned short a_lds[64 * 136];
    __shared__ unsigned short b_lds[128 * 136];
    int tid = threadIdx.x;
    int m0 = blockIdx.x * 64;
    stage128(Hbf + (size_t)m0 * 128, a_lds, 64, tid);
    stage128(WaT, b_lds, 128, tid);
    __syncthreads();
    int w = tid >> 6, l = tid & 63, q = l >> 4, r = l & 15;
    f32x4 acc[8] = {};
    #pragma unroll
    for (int kc = 0; kc < 4; ++kc) {
        bf16x8 a = *(const bf16x8*)(a_lds + (w * 16 + r) * 136 + kc * 32 + q * 8);
        #pragma unroll
        for (int nt = 0; nt < 8; ++nt) {
            bf16x8 b = *(const bf16x8*)(b_lds + (nt * 16 + r) * 136 + kc * 32 + q * 8);
            acc[nt] = mfma16(a, b, acc[nt]);
        }
    }
    #pragma unroll
    for (int nt = 0; nt < 8; ++nt) {
        int col = nt * 16 + r;
        float bav = ba[col];
        #pragma unroll
        for (int j = 0; j < 4; ++j) {
            int row = m0 + w * 16 + q * 4 + j;
            T1[(size_t)row * 128 + col] = f2bf(tanh_f(acc[nt][j] + bav));
        }
    }
}

// ---------------- beta = softmax(T1 @ Va) ----------------
__global__ __launch_bounds__(256) void k_att2(const unsigned short* __restrict__ T1,
                                              const unsigned short* __restrict__ VaT,
                                              unsigned short* __restrict__ beta) {
    __shared__ __align__(16) char smem[52224];
    unsigned short* a_lds = (unsigned short*)smem;
    unsigned short* b_lds = (unsigned short*)(smem + 17408);
    float* lg  = (float*)smem;
    float* inv = (float*)(smem + 34048);
    int tid = threadIdx.x;
    int m0 = blockIdx.x * 64;
    stage128(T1 + (size_t)m0 * 128, a_lds, 64, tid);
    stage128(VaT, b_lds, 128, tid);
    __syncthreads();
    int w = tid >> 6, l = tid & 63, q = l >> 4, r = l & 15;
    f32x4 acc[8] = {};
    #pragma unroll
    for (int kc = 0; kc < 4; ++kc) {
        bf16x8 a = *(const bf16x8*)(a_lds + (w * 16 + r) * 136 + kc * 32 + q * 8);
        #pragma unroll
        for (int nt = 0; nt < 8; ++nt) {
            bf16x8 b = *(const bf16x8*)(b_lds + (nt * 16 + r) * 136 + kc * 32 + q * 8);
            acc[nt] = mfma16(a, b, acc[nt]);
        }
    }
    __syncthreads();
    #pragma unroll
    for (int nt = 0; nt < 8; ++nt)
        #pragma unroll
        for (int j = 0; j < 4; ++j)
            lg[(w * 16 + q * 4 + j) * 133 + nt * 16 + r] = acc[nt][j];
    __syncthreads();
    if (tid < 64) {
        float mx = -1e30f;
        for (int c = 0; c < 128; ++c) mx = fmaxf(mx, lg[tid * 133 + c]);
        float s = 0.f;
        for (int c = 0; c < 128; ++c) {
            float e = __expf(lg[tid * 133 + c] - mx);
            lg[tid * 133 + c] = e;
            s += e;
        }
        inv[tid] = 1.0f / s;
    }
    __syncthreads();
    for (int i = tid; i < 64 * 128; i += 256) {
        int rr = i >> 7, cc = i & 127;
        beta[(size_t)(m0 + rr) * 128 + cc] = f2bf(lg[rr * 133 + cc] * inv[rr]);
    }
}

// ---------------- poolT[t*512+b][d] = beta[b] @ H[b] ----------------
__global__ __launch_bounds__(256) void k_pool(const unsigned short* __restrict__ beta,
                                              const unsigned short* __restrict__ HT,
                                              unsigned short* __restrict__ poolT) {
    __shared__ unsigned short a_lds[64 * 136];
    __shared__ unsigned short b_lds[128 * 136];
    int tid = threadIdx.x;
    int b = blockIdx.x >> 1, mh = blockIdx.x & 1;
    stage128(beta + ((size_t)b * 128 + mh * 64) * 128, a_lds, 64, tid);
    stage128(HT + (size_t)b * 16384, b_lds, 128, tid);
    __syncthreads();
    int w = tid >> 6, l = tid & 63, q = l >> 4, r = l & 15;
    f32x4 acc[8] = {};
    #pragma unroll
    for (int kc = 0; kc < 4; ++kc) {
        bf16x8 a = *(const bf16x8*)(a_lds + (w * 16 + r) * 136 + kc * 32 + q * 8);
        #pragma unroll
        for (int nt = 0; nt < 8; ++nt) {
            bf16x8 bb = *(const bf16x8*)(b_lds + (nt * 16 + r) * 136 + kc * 32 + q * 8);
            acc[nt] = mfma16(a, bb, acc[nt]);
        }
    }
    #pragma unroll
    for (int nt = 0; nt < 8; ++nt)
        #pragma unroll
        for (int j = 0; j < 4; ++j) {
            int t = mh * 64 + w * 16 + q * 4 + j;
            poolT[((size_t)t * 512 + b) * 128 + nt * 16 + r] = f2bf(acc[nt][j]);
        }
}

// ---------------- Gx = pool @ W + bias, packed [g][t][w][gate-pair][lane][8] ----------------
__global__ __launch_bounds__(256) void k_gx(const unsigned short* __restrict__ poolT,
                                            const unsigned short* __restrict__ WT,
                                            const float* __restrict__ bias,
                                            unsigned short* __restrict__ Gxp) {
    __shared__ unsigned short a_lds[64 * 136];
    __shared__ unsigned short b_lds[128 * 136];
    int tid = threadIdx.x;
    int mblk = blockIdx.x >> 3, nb = blockIdx.x & 7;
    int t = mblk >> 3, gblk = mblk & 7;
    int m0 = mblk * 64, n0 = nb * 128;
    stage128(poolT + (size_t)m0 * 128, a_lds, 64, tid);
    stage128(WT + (size_t)n0 * 128, b_lds, 128, tid);
    __syncthreads();
    int w = tid >> 6, l = tid & 63, q = l >> 4, r = l & 15;
    f32x4 acc[8] = {};
    #pragma unroll
    for (int kc = 0; kc < 4; ++kc) {
        bf16x8 a = *(const bf16x8*)(a_lds + (w * 16 + r) * 136 + kc * 32 + q * 8);
        #pragma unroll
        for (int nt = 0; nt < 8; ++nt) {
            bf16x8 bb = *(const bf16x8*)(b_lds + (nt * 16 + r) * 136 + kc * 32 + q * 8);
            acc[nt] = mfma16(a, bb, acc[nt]);
        }
    }
    int g_seq = gblk * 4 + w;   // wave's 16 rows = one sequential batch group
    #pragma unroll
    for (int np2 = 0; np2 < 4; ++np2) {
        int nt0 = np2 * 2, nt1 = nt0 + 1;
        int col0 = n0 + nt0 * 16, col1 = n0 + nt1 * 16;
        float bv0 = bias[col0 + r], bv1 = bias[col1 + r];
        int w_seq = (col0 & 255) >> 5;
        int gate = col0 >> 8;
        size_t idx8 = ((((size_t)g_seq * 128 + t) * 8 + w_seq) * 4 + gate) * 64 + l;
        bf16x8 o;
        o[0] = (short)f2bf(acc[nt0][0] + bv0);
        o[1] = (short)f2bf(acc[nt0][1] + bv0);
        o[2] = (short)f2bf(acc[nt0][2] + bv0);
        o[3] = (short)f2bf(acc[nt0][3] + bv0);
        o[4] = (short)f2bf(acc[nt1][0] + bv1);
        o[5] = (short)f2bf(acc[nt1][1] + bv1);
        o[6] = (short)f2bf(acc[nt1][2] + bv1);
        o[7] = (short)f2bf(acc[nt1][3] + bv1);
        *(bf16x8*)(Gxp + idx8 * 8) = o;   // 16B/lane, lane-contiguous
    }
}

// ---------------- sequential LSTM: 32 blocks x 16 batch rows ----------------
// dynamic LDS: U kc3-4 (131072 B) | h frag-order dbuf (16384 B) | ypart (1024 B)
__global__ __launch_bounds__(512)
void k_seq(const unsigned short* __restrict__ Gxp,
           const unsigned short* __restrict__ Upk,
           const float* __restrict__ Wy,
           const float* __restrict__ fcW,
           const float* __restrict__ fcb,
           const float* __restrict__ y0,
           float* __restrict__ out) {
    extern __shared__ __align__(16) char dynbuf[];
    unsigned short* u2   = (unsigned short*)dynbuf;             // 65536 shorts (kc3,4)
    unsigned short* h_fl = (unsigned short*)(dynbuf + 131072);  // 2 x 4096 shorts
    float* ypart         = (float*)(dynbuf + 147456);           // [2][8][16]

    int tid = threadIdx.x;
    int g = blockIdx.x;
    int w = tid >> 6, l = tid & 63, q = l >> 4, r = l & 15;
    float fc_b0 = fcb[0];

    // AGPR-pinned U: kc 0..2 (96 AGPRs) — opaque def, cannot be rematerialized.
    bf16x8 u_res[3][8];
    #pragma unroll
    for (int kc = 0; kc < 3; ++kc)
        #pragma unroll
        for (int tt = 0; tt < 8; ++tt) {
            u_res[kc][tt] = *(const bf16x8*)(Upk + (size_t)(((w * 8 + kc) * 8 + tt) * 64 + l) * 8);
            asm volatile("" : "+a"(u_res[kc][tt]));
        }

    // LDS-resident U: kc 3..4
    #pragma unroll
    for (int kcL = 0; kcL < 2; ++kcL)
        #pragma unroll
        for (int tt = 0; tt < 8; ++tt) {
            size_t gofs = (size_t)(((w * 8 + 3 + kcL) * 8 + tt) * 64 + l) * 8;
            size_t lofs = (size_t)(((w * 2 + kcL) * 8 + tt) * 64 + l) * 8;
            *(bf16x8*)(u2 + lofs) = *(const bf16x8*)(Upk + gofs);
        }

    float wy_r[8], fw[2];
    #pragma unroll
    for (int tt = 0; tt < 8; ++tt)
        wy_r[tt] = Wy[(tt >> 1) * 256 + w * 32 + (tt & 1) * 16 + r];
    fw[0] = fcW[w * 32 + r];
    fw[1] = fcW[w * 32 + 16 + r];
    float c_st[2][4] = {};

    for (int i = tid; i < 4096; i += 512) h_fl[i] = 0;   // h(0) = 0, frag-order buf 0
    if (tid < 128) {
        int ww = tid >> 4, rw = tid & 15;
        ypart[ww * 16 + rw] = (ww == 0) ? (y0[g * 16 + rw] - fc_b0) : 0.0f;
        ypart[128 + ww * 16 + rw] = 0.0f;
    }
    __syncthreads();

    float* outh = out + 512;
    const bf16x8* gq = (const bf16x8*)Gxp;

    // Gx software pipeline: preload t=0
    bf16x8 gx_cur[4];
    {
        size_t base = (((size_t)g * 128 * 8 + w) * 4) * 64 + l;
        #pragma unroll
        for (int gate = 0; gate < 4; ++gate) gx_cur[gate] = gq[base + (size_t)gate * 64];
    }

    for (int t = 0; t < 128; ++t) {
        int p = t & 1, np = p ^ 1;
        unsigned short* hp = h_fl + p * 4096;
        unsigned short* hn = h_fl + np * 4096;
        float* ypp = ypart + p * 128;
        float* ypn = ypart + np * 128;

        // ---- issue next-step Gx (full step of latency hiding) ----
        bf16x8 gx_nxt[4];
        {
            int tn = (t < 127) ? t + 1 : 127;
            size_t base = ((((size_t)g * 128 + tn) * 8 + w) * 4) * 64 + l;
            #pragma unroll
            for (int gate = 0; gate < 4; ++gate) gx_nxt[gate] = gq[base + (size_t)gate * 64];
        }
        // ---- issue streamed U kc5, kc6 ----
        bf16x8 ub5[8], ub6[8];
        #pragma unroll
        for (int tt = 0; tt < 8; ++tt)
            ub5[tt] = *(const bf16x8*)(Upk + (size_t)(((w * 8 + 5) * 8 + tt) * 64 + l) * 8);
        #pragma unroll
        for (int tt = 0; tt < 8; ++tt)
            ub6[tt] = *(const bf16x8*)(Upk + (size_t)(((w * 8 + 6) * 8 + tt) * 64 + l) * 8);

        // ---- y_prev assembly + acc init with Wy outer product ----
        float yp[4];
        #pragma unroll
        for (int j = 0; j < 4; ++j) {
            float s = fc_b0;
            #pragma unroll
            for (int ww = 0; ww < 8; ++ww) s += ypp[ww * 16 + q * 4 + j];
            yp[j] = s;
        }
        f32x4 acc[8];
        #pragma unroll
        for (int tt = 0; tt < 8; ++tt) {
            acc[tt][0] = yp[0] * wy_r[tt];
            acc[tt][1] = yp[1] * wy_r[tt];
            acc[tt][2] = yp[2] * wy_r[tt];
            acc[tt][3] = yp[3] * wy_r[tt];
        }

        // ---- AGPR kcs 0..2 ----
        #pragma unroll
        for (int kc = 0; kc < 3; ++kc) {
            bf16x8 a = *(const bf16x8*)(hp + ((kc * 4 + q) * 16 + r) * 8);
            #pragma unroll
            for (int tt = 0; tt < 8; ++tt) acc[tt] = mfma16(a, u_res[kc][tt], acc[tt]);
        }
        // ---- LDS kc3 ----
        {
            bf16x8 a = *(const bf16x8*)(hp + ((3 * 4 + q) * 16 + r) * 8);
            #pragma unroll
            for (int tt = 0; tt < 8; ++tt) {
                bf16x8 u = *(const bf16x8*)(u2 + (size_t)((w * 2 * 8 + tt) * 64 + l) * 8);
                acc[tt] = mfma16(a, u, acc[tt]);
            }
        }
        // ---- streamed kc5 (consumes ub5) ----
        {
            bf16x8 a = *(const bf16x8*)(hp + ((5 * 4 + q) * 16 + r) * 8);
            #pragma unroll
            for (int tt = 0; tt < 8; ++tt) acc[tt] = mfma16(a, ub5[tt], acc[tt]);
        }
        // ---- issue kc7 now that ub5 regs are free ----
        bf16x8 ub7[8];
        #pragma unroll
        for (int tt = 0; tt < 8; ++tt)
            ub7[tt] = *(const bf16x8*)(Upk + (size_t)(((w * 8 + 7) * 8 + tt) * 64 + l) * 8);
        // ---- LDS kc4 ----
        {
            bf16x8 a = *(const bf16x8*)(hp + ((4 * 4 + q) * 16 + r) * 8);
            #pragma unroll
            for (int tt = 0; tt < 8; ++tt) {
                bf16x8 u = *(const bf16x8*)(u2 + (size_t)(((w * 2 + 1) * 8 + tt) * 64 + l) * 8);
                acc[tt] = mfma16(a, u, acc[tt]);
            }
        }
        // ---- streamed kc6, kc7 ----
        {
            bf16x8 a = *(const bf16x8*)(hp + ((6 * 4 + q) * 16 + r) * 8);
            #pragma unroll
            for (int tt = 0; tt < 8; ++tt) acc[tt] = mfma16(a, ub6[tt], acc[tt]);
        }
        {
            bf16x8 a = *(const bf16x8*)(hp + ((7 * 4 + q) * 16 + r) * 8);
            #pragma unroll
            for (int tt = 0; tt < 8; ++tt) acc[tt] = mfma16(a, ub7[tt], acc[tt]);
        }

        // ---- LSTM cell (gx_cur loaded a full step ago) ----
        float ypj[4] = {0.f, 0.f, 0.f, 0.f};
        #pragma unroll
        for (int sub = 0; sub < 2; ++sub) {
            #pragma unroll
            for (int j = 0; j < 4; ++j) {
                float iv = sigm(acc[0 + sub][j] + bf2f((unsigned short)gx_cur[0][sub * 4 + j]));
                float fv = sigm(acc[2 + sub][j] + bf2f((unsigned short)gx_cur[1][sub * 4 + j]));
                float gv = tanh_f(acc[4 + sub][j] + bf2f((unsigned short)gx_cur[2][sub * 4 + j]));
                float ov = sigm(acc[6 + sub][j] + bf2f((unsigned short)gx_cur[3][sub * 4 + j]));
                float c = fv * c_st[sub][j] + iv * gv;
                c_st[sub][j] = c;
                float hv = ov * tanh_f(c);
                int row = q * 4 + j, k = w * 32 + sub * 16 + r;
                hn[((w * 4 + sub * 2 + (r >> 3)) * 16 + row) * 8 + (r & 7)] = f2bf(hv);
                outh[((size_t)(g * 16 + row) * 128 + t) * 256 + k] = hv;  // fire-and-forget
                ypj[j] += hv * fw[sub];
            }
        }
        #pragma unroll
        for (int j = 0; j < 4; ++j) {   // reduce y partial over the 16-lane group
            float v = ypj[j];
            v += __shfl_xor(v, 1);
            v += __shfl_xor(v, 2);
            v += __shfl_xor(v, 4);
            v += __shfl_xor(v, 8);
            if (r == 0) ypn[w * 16 + q * 4 + j] = v;
        }
        #pragma unroll
        for (int gate = 0; gate < 4; ++gate) gx_cur[gate] = gx_nxt[gate];

        // raw barrier: LDS visibility only; outh stores drain in background.
        asm volatile("s_waitcnt lgkmcnt(0)\n\ts_barrier" ::: "memory");
    }
    if (tid < 16) {
        float y = fc_b0;
        #pragma unroll
        for (int ww = 0; ww < 8; ++ww) y += ypart[ww * 16 + tid];
        out[g * 16 + tid] = y;
    }
}

extern "C" void kernel_launch(void* const* d_in, const int* in_sizes, int n_in,
                              void* d_out, int out_size, void* d_ws, size_t ws_size,
                              hipStream_t stream) {
    const float* H    = (const float*)d_in[0];
    const float* y0   = (const float*)d_in[1];
    const float* Wa   = (const float*)d_in[2];
    // d_in[3] = Ua: multiplied by an all-zero state in the reference -> unused
    const float* ba   = (const float*)d_in[4];
    const float* Va   = (const float*)d_in[5];
    const float* W    = (const float*)d_in[6];
    const float* U    = (const float*)d_in[7];
    const float* bias = (const float*)d_in[8];
    const float* Wy   = (const float*)d_in[9];
    const float* fcW  = (const float*)d_in[10];
    const float* fcb  = (const float*)d_in[11];
    float* out = (float*)d_out;
    char* ws = (char*)d_ws;

    unsigned short* Hbf   = (unsigned short*)(ws);
    unsigned short* HT    = (unsigned short*)(ws + 16777216);
    unsigned short* T1    = (unsigned short*)(ws + 2 * 16777216);
    unsigned short* beta  = (unsigned short*)(ws + 3 * 16777216);
    unsigned short* poolT = (unsigned short*)(ws + 4 * 16777216);
    unsigned short* Gxp   = (unsigned short*)(ws + (size_t)5 * 16777216);        // 134.2 MB
    unsigned short* WaT   = (unsigned short*)(ws + (size_t)5 * 16777216 + 134217728);
    unsigned short* VaT   = WaT + 16384;
    unsigned short* WT    = VaT + 16384;
    unsigned short* Upk   = WT + 131072;

    hipFuncSetAttribute((const void*)k_seq, hipFuncAttributeMaxDynamicSharedMemorySize, 148480);

    hipLaunchKernelGGL(k_prepw, dim3(1664), dim3(256), 0, stream, Wa, Va, W, U, WaT, VaT, WT, Upk);
    hipLaunchKernelGGL(k_preph, dim3(8192), dim3(256), 0, stream, H, Hbf, HT);
    hipLaunchKernelGGL(k_att1, dim3(1024), dim3(256), 0, stream, Hbf, WaT, ba, T1);
    hipLaunchKernelGGL(k_att2, dim3(1024), dim3(256), 0, stream, T1, VaT, beta);
    hipLaunchKernelGGL(k_pool, dim3(1024), dim3(256), 0, stream, beta, HT, poolT);
    hipLaunchKernelGGL(k_gx, dim3(8192), dim3(256), 0, stream, poolT, WT, bias, Gxp);
    hipLaunchKernelGGL(k_seq, dim3(32), dim3(512), 148480, stream, Gxp, Upk, Wy, fcW, fcb, y0, out);
}

// Round 7
// 1293.194 us; speedup vs baseline: 1.1281x; 1.1281x over previous
//
#include <hip/hip_runtime.h>
#include <hip/hip_bf16.h>

// Shapes: B=512, S=128, D=128, HS=256, 4HS=1024, O=1.
// k_seq v7: 32 blocks x 512 threads, no cross-block exchange.
// U residency (time-invariant -> resident or re-fetched, no "prefetch"):
//   kc0-1 in LDS (128 KB), kc2-6 + kc7{tt6,7} pinned in AGPRs (168),
//   kc7{tt0..5} streamed (48 KB/step), 3 frags/pass issued a phase early.
// Cell split into 2 passes over col-halves so peak arch regs ~84 -> total
// ~252 <= 256 (2 waves/SIMD): the allocator can finally keep the pins.

using bf16x8 = __attribute__((ext_vector_type(8))) short;
using f32x4  = __attribute__((ext_vector_type(4))) float;

#define DEV static __device__ __forceinline__

DEV unsigned short f2bf(float x) {
    unsigned u = __float_as_uint(x);
    u += 0x7fffu + ((u >> 16) & 1u);          // round-to-nearest-even
    return (unsigned short)(u >> 16);
}
DEV float bf2f(unsigned short s) { return __uint_as_float(((unsigned)s) << 16); }
DEV float sigm(float x) { return 1.0f / (1.0f + __expf(-x)); }
DEV float tanh_f(float x) { float e = __expf(2.0f * x); return 1.0f - 2.0f / (e + 1.0f); }
DEV f32x4 mfma16(bf16x8 a, bf16x8 b, f32x4 c) {
    return __builtin_amdgcn_mfma_f32_16x16x32_bf16(a, b, c, 0, 0, 0);
}

// stage rows x 128 bf16 (row stride 128) into LDS with padded stride 136
DEV void stage128(const unsigned short* __restrict__ src, unsigned short* dst, int rows, int tid) {
    int chunks = rows * 16;
    for (int i = tid; i < chunks; i += 256) {
        int r = i >> 4, c = (i & 15) << 3;
        *(bf16x8*)(dst + r * 136 + c) = *(const bf16x8*)(src + r * 128 + c);
    }
}

// ---------------- prep kernels ----------------
__global__ void k_prepw(const float* __restrict__ Wa, const float* __restrict__ Va,
                        const float* __restrict__ W, const float* __restrict__ U,
                        unsigned short* __restrict__ WaT, unsigned short* __restrict__ VaT,
                        unsigned short* __restrict__ WT, unsigned short* __restrict__ Upk) {
    int idx = blockIdx.x * 256 + threadIdx.x;
    if (idx < 16384) {
        int n = idx >> 7, k = idx & 127;
        WaT[idx] = f2bf(Wa[k * 128 + n]);
    } else if (idx < 32768) {
        int i = idx - 16384;
        int n = i >> 7, k = i & 127;
        VaT[i] = f2bf(Va[k * 128 + n]);
    } else if (idx < 163840) {
        int i = idx - 32768;
        int n = i >> 7, k = i & 127;
        WT[i] = f2bf(W[k * 1024 + n]);
    } else if (idx < 425984) {
        int i = idx - 163840;   // layout: ((((w*8+kc)*8+tt)*64+l)*8+j
        int j = i & 7, ll = (i >> 3) & 63, tt = (i >> 9) & 7, kc = (i >> 12) & 7, w = i >> 15;
        int k = kc * 32 + (ll >> 4) * 8 + j;
        int n = (tt >> 1) * 256 + w * 32 + (tt & 1) * 16 + (ll & 15);
        Upk[i] = f2bf(U[k * 1024 + n]);
    }
}

__global__ void k_preph(const float* __restrict__ H, unsigned short* __restrict__ Hbf,
                        unsigned short* __restrict__ HT) {
    for (size_t idx = (size_t)blockIdx.x * 256 + threadIdx.x; idx < 16777216u;
         idx += (size_t)gridDim.x * 256) {
        if (idx < 8388608u) {
            Hbf[idx] = f2bf(H[idx]);
        } else {
            size_t i = idx - 8388608u;
            int b = (int)(i >> 14);
            int rem = (int)(i & 16383);
            int d = rem >> 7, s = rem & 127;
            HT[i] = f2bf(H[((size_t)b * 128 + s) * 128 + d]);
        }
    }
}

// ---------------- T1 = tanh(H @ Wa + ba) ----------------
__global__ __launch_bounds__(256) void k_att1(const unsigned short* __restrict__ Hbf,
                                              const unsigned short* __restrict__ WaT,
                                              const float* __restrict__ ba,
                                              unsigned short* __restrict__ T1) {
    __shared__ unsigned short a_lds[64 * 136];
    __shared__ unsigned short b_lds[128 * 136];
    int tid = threadIdx.x;
    int m0 = blockIdx.x * 64;
    stage128(Hbf + (size_t)m0 * 128, a_lds, 64, tid);
    stage128(WaT, b_lds, 128, tid);
    __syncthreads();
    int w = tid >> 6, l = tid & 63, q = l >> 4, r = l & 15;
    f32x4 acc[8] = {};
    #pragma unroll
    for (int kc = 0; kc < 4; ++kc) {
        bf16x8 a = *(const bf16x8*)(a_lds + (w * 16 + r) * 136 + kc * 32 + q * 8);
        #pragma unroll
        for (int nt = 0; nt < 8; ++nt) {
            bf16x8 b = *(const bf16x8*)(b_lds + (nt * 16 + r) * 136 + kc * 32 + q * 8);
            acc[nt] = mfma16(a, b, acc[nt]);
        }
    }
    #pragma unroll
    for (int nt = 0; nt < 8; ++nt) {
        int col = nt * 16 + r;
        float bav = ba[col];
        #pragma unroll
        for (int j = 0; j < 4; ++j) {
            int row = m0 + w * 16 + q * 4 + j;
            T1[(size_t)row * 128 + col] = f2bf(tanh_f(acc[nt][j] + bav));
        }
    }
}

// ---------------- beta = softmax(T1 @ Va) ----------------
__global__ __launch_bounds__(256) void k_att2(const unsigned short* __restrict__ T1,
                                              const unsigned short* __restrict__ VaT,
                                              unsigned short* __restrict__ beta) {
    __shared__ __align__(16) char smem[52224];
    unsigned short* a_lds = (unsigned short*)smem;
    unsigned short* b_lds = (unsigned short*)(smem + 17408);
    float* lg  = (float*)smem;
    float* inv = (float*)(smem + 34048);
    int tid = threadIdx.x;
    int m0 = blockIdx.x * 64;
    stage128(T1 + (size_t)m0 * 128, a_lds, 64, tid);
    stage128(VaT, b_lds, 128, tid);
    __syncthreads();
    int w = tid >> 6, l = tid & 63, q = l >> 4, r = l & 15;
    f32x4 acc[8] = {};
    #pragma unroll
    for (int kc = 0; kc < 4; ++kc) {
        bf16x8 a = *(const bf16x8*)(a_lds + (w * 16 + r) * 136 + kc * 32 + q * 8);
        #pragma unroll
        for (int nt = 0; nt < 8; ++nt) {
            bf16x8 b = *(const bf16x8*)(b_lds + (nt * 16 + r) * 136 + kc * 32 + q * 8);
            acc[nt] = mfma16(a, b, acc[nt]);
        }
    }
    __syncthreads();
    #pragma unroll
    for (int nt = 0; nt < 8; ++nt)
        #pragma unroll
        for (int j = 0; j < 4; ++j)
            lg[(w * 16 + q * 4 + j) * 133 + nt * 16 + r] = acc[nt][j];
    __syncthreads();
    if (tid < 64) {
        float mx = -1e30f;
        for (int c = 0; c < 128; ++c) mx = fmaxf(mx, lg[tid * 133 + c]);
        float s = 0.f;
        for (int c = 0; c < 128; ++c) {
            float e = __expf(lg[tid * 133 + c] - mx);
            lg[tid * 133 + c] = e;
            s += e;
        }
        inv[tid] = 1.0f / s;
    }
    __syncthreads();
    for (int i = tid; i < 64 * 128; i += 256) {
        int rr = i >> 7, cc = i & 127;
        beta[(size_t)(m0 + rr) * 128 + cc] = f2bf(lg[rr * 133 + cc] * inv[rr]);
    }
}

// ---------------- poolT[t*512+b][d] = beta[b] @ H[b] ----------------
__global__ __launch_bounds__(256) void k_pool(const unsigned short* __restrict__ beta,
                                              const unsigned short* __restrict__ HT,
                                              unsigned short* __restrict__ poolT) {
    __shared__ unsigned short a_lds[64 * 136];
    __shared__ unsigned short b_lds[128 * 136];
    int tid = threadIdx.x;
    int b = blockIdx.x >> 1, mh = blockIdx.x & 1;
    stage128(beta + ((size_t)b * 128 + mh * 64) * 128, a_lds, 64, tid);
    stage128(HT + (size_t)b * 16384, b_lds, 128, tid);
    __syncthreads();
    int w = tid >> 6, l = tid & 63, q = l >> 4, r = l & 15;
    f32x4 acc[8] = {};
    #pragma unroll
    for (int kc = 0; kc < 4; ++kc) {
        bf16x8 a = *(const bf16x8*)(a_lds + (w * 16 + r) * 136 + kc * 32 + q * 8);
        #pragma unroll
        for (int nt = 0; nt < 8; ++nt) {
            bf16x8 bb = *(const bf16x8*)(b_lds + (nt * 16 + r) * 136 + kc * 32 + q * 8);
            acc[nt] = mfma16(a, bb, acc[nt]);
        }
    }
    #pragma unroll
    for (int nt = 0; nt < 8; ++nt)
        #pragma unroll
        for (int j = 0; j < 4; ++j) {
            int t = mh * 64 + w * 16 + q * 4 + j;
            poolT[((size_t)t * 512 + b) * 128 + nt * 16 + r] = f2bf(acc[nt][j]);
        }
}

// ---------------- Gx = pool @ W + bias, packed [g][t][w][gate][lane][8] ----------------
__global__ __launch_bounds__(256) void k_gx(const unsigned short* __restrict__ poolT,
                                            const unsigned short* __restrict__ WT,
                                            const float* __restrict__ bias,
                                            unsigned short* __restrict__ Gxp) {
    __shared__ unsigned short a_lds[64 * 136];
    __shared__ unsigned short b_lds[128 * 136];
    int tid = threadIdx.x;
    int mblk = blockIdx.x >> 3, nb = blockIdx.x & 7;
    int t = mblk >> 3, gblk = mblk & 7;
    int m0 = mblk * 64, n0 = nb * 128;
    stage128(poolT + (size_t)m0 * 128, a_lds, 64, tid);
    stage128(WT + (size_t)n0 * 128, b_lds, 128, tid);
    __syncthreads();
    int w = tid >> 6, l = tid & 63, q = l >> 4, r = l & 15;
    f32x4 acc[8] = {};
    #pragma unroll
    for (int kc = 0; kc < 4; ++kc) {
        bf16x8 a = *(const bf16x8*)(a_lds + (w * 16 + r) * 136 + kc * 32 + q * 8);
        #pragma unroll
        for (int nt = 0; nt < 8; ++nt) {
            bf16x8 bb = *(const bf16x8*)(b_lds + (nt * 16 + r) * 136 + kc * 32 + q * 8);
            acc[nt] = mfma16(a, bb, acc[nt]);
        }
    }
    int g_seq = gblk * 4 + w;   // wave's 16 rows = one sequential batch group
    #pragma unroll
    for (int np2 = 0; np2 < 4; ++np2) {
        int nt0 = np2 * 2, nt1 = nt0 + 1;
        int col0 = n0 + nt0 * 16, col1 = n0 + nt1 * 16;
        float bv0 = bias[col0 + r], bv1 = bias[col1 + r];
        int w_seq = (col0 & 255) >> 5;
        int gate = col0 >> 8;
        size_t idx8 = ((((size_t)g_seq * 128 + t) * 8 + w_seq) * 4 + gate) * 64 + l;
        bf16x8 o;
        o[0] = (short)f2bf(acc[nt0][0] + bv0);
        o[1] = (short)f2bf(acc[nt0][1] + bv0);
        o[2] = (short)f2bf(acc[nt0][2] + bv0);
        o[3] = (short)f2bf(acc[nt0][3] + bv0);
        o[4] = (short)f2bf(acc[nt1][0] + bv1);
        o[5] = (short)f2bf(acc[nt1][1] + bv1);
        o[6] = (short)f2bf(acc[nt1][2] + bv1);
        o[7] = (short)f2bf(acc[nt1][3] + bv1);
        *(bf16x8*)(Gxp + idx8 * 8) = o;   // 16B/lane, lane-contiguous
    }
}

// ---------------- sequential LSTM: 32 blocks x 16 batch rows ----------------
// dynamic LDS: U kc0-1 (131072 B) | h frag-order dbuf (16384 B) | ypart (1024 B)
__global__ __launch_bounds__(512)
void k_seq(const unsigned short* __restrict__ Gxp,
           const unsigned short* __restrict__ Upk,
           const float* __restrict__ Wy,
           const float* __restrict__ fcW,
           const float* __restrict__ fcb,
           const float* __restrict__ y0,
           float* __restrict__ out) {
    extern __shared__ __align__(16) char dynbuf[];
    unsigned short* u2   = (unsigned short*)dynbuf;             // kc0-1 (65536 shorts)
    unsigned short* h_fl = (unsigned short*)(dynbuf + 131072);  // 2 x 4096 shorts
    float* ypart         = (float*)(dynbuf + 147456);           // [2][8][16]

    int tid = threadIdx.x;
    int g = blockIdx.x;
    int w = tid >> 6, l = tid & 63, q = l >> 4, r = l & 15;
    float fc_b0 = fcb[0];

    // AGPR-resident U: kc2-6 all tt (160 AGPRs) + kc7 tt{6,7} (8 AGPRs)
    bf16x8 u_res[5][8];
    #pragma unroll
    for (int i = 0; i < 5; ++i)
        #pragma unroll
        for (int tt = 0; tt < 8; ++tt) {
            u_res[i][tt] = *(const bf16x8*)(Upk + (size_t)(((w * 8 + 2 + i) * 8 + tt) * 64 + l) * 8);
            asm volatile("" : "+a"(u_res[i][tt]));
        }
    bf16x8 u7p[2];
    #pragma unroll
    for (int i = 0; i < 2; ++i) {
        u7p[i] = *(const bf16x8*)(Upk + (size_t)(((w * 8 + 7) * 8 + 6 + i) * 64 + l) * 8);
        asm volatile("" : "+a"(u7p[i]));
    }

    // LDS-resident U: kc0-1 (each lane copies its own fragment)
    #pragma unroll
    for (int kcL = 0; kcL < 2; ++kcL)
        #pragma unroll
        for (int tt = 0; tt < 8; ++tt) {
            size_t gofs = (size_t)(((w * 8 + kcL) * 8 + tt) * 64 + l) * 8;
            size_t lofs = (size_t)(((w * 2 + kcL) * 8 + tt) * 64 + l) * 8;
            *(bf16x8*)(u2 + lofs) = *(const bf16x8*)(Upk + gofs);
        }

    float wy_r[8], fw[2];
    #pragma unroll
    for (int tt = 0; tt < 8; ++tt)
        wy_r[tt] = Wy[(tt >> 1) * 256 + w * 32 + (tt & 1) * 16 + r];
    fw[0] = fcW[w * 32 + r];
    fw[1] = fcW[w * 32 + 16 + r];
    float c_st[2][4] = {};

    for (int i = tid; i < 4096; i += 512) h_fl[i] = 0;   // h(0) = 0, frag-order buf 0
    if (tid < 128) {
        int ww = tid >> 4, rw = tid & 15;
        ypart[ww * 16 + rw] = (ww == 0) ? (y0[g * 16 + rw] - fc_b0) : 0.0f;
        ypart[128 + ww * 16 + rw] = 0.0f;
    }
    __syncthreads();

    float* outh = out + 512;
    const bf16x8* gq = (const bf16x8*)Gxp;
    const unsigned short* u7base = Upk + (size_t)((w * 8 + 7) * 8) * 64 * 8;

    for (int t = 0; t < 128; ++t) {
        int p = t & 1, np = p ^ 1;
        unsigned short* hp = h_fl + p * 4096;
        unsigned short* hn = h_fl + np * 4096;
        float* ypp = ypart + p * 128;
        float* ypn = ypart + np * 128;

        // ---- step top: Gx (4x dwordx4) + pass0 streamed kc7 frags (tt 0,2,4) ----
        bf16x8 gxq[4];
        {
            size_t base = ((((size_t)g * 128 + t) * 8 + w) * 4) * 64 + l;
            #pragma unroll
            for (int gate = 0; gate < 4; ++gate) gxq[gate] = gq[base + (size_t)gate * 64];
        }
        bf16x8 u7s[3];
        #pragma unroll
        for (int i = 0; i < 3; ++i)
            u7s[i] = *(const bf16x8*)(u7base + (size_t)((2 * i) * 64 + l) * 8);

        // ---- y_prev (same for both passes) ----
        float yp[4];
        #pragma unroll
        for (int j = 0; j < 4; ++j) {
            float s = fc_b0;
            #pragma unroll
            for (int ww = 0; ww < 8; ++ww) s += ypp[ww * 16 + q * 4 + j];
            yp[j] = s;
        }
        float ypj[4] = {0.f, 0.f, 0.f, 0.f};

        // ================= PASS 0 (sub = 0, tt = gate*2) =================
        {
            f32x4 acc[4];
            #pragma unroll
            for (int gate = 0; gate < 4; ++gate) {
                float wv = wy_r[gate * 2];
                acc[gate][0] = yp[0] * wv; acc[gate][1] = yp[1] * wv;
                acc[gate][2] = yp[2] * wv; acc[gate][3] = yp[3] * wv;
            }
            #pragma unroll
            for (int kcL = 0; kcL < 2; ++kcL) {       // kc0-1 from LDS
                bf16x8 a = *(const bf16x8*)(hp + ((kcL * 4 + q) * 16 + r) * 8);
                #pragma unroll
                for (int gate = 0; gate < 4; ++gate) {
                    bf16x8 b = *(const bf16x8*)(u2 + (size_t)(((w * 2 + kcL) * 8 + gate * 2) * 64 + l) * 8);
                    acc[gate] = mfma16(a, b, acc[gate]);
                }
            }
            #pragma unroll
            for (int i = 0; i < 5; ++i) {             // kc2-6 from AGPR
                bf16x8 a = *(const bf16x8*)(hp + (((2 + i) * 4 + q) * 16 + r) * 8);
                #pragma unroll
                for (int gate = 0; gate < 4; ++gate)
                    acc[gate] = mfma16(a, u_res[i][gate * 2], acc[gate]);
            }
            {                                          // kc7: streamed tt0,2,4 + pinned tt6
                bf16x8 a = *(const bf16x8*)(hp + ((7 * 4 + q) * 16 + r) * 8);
                acc[0] = mfma16(a, u7s[0], acc[0]);
                acc[1] = mfma16(a, u7s[1], acc[1]);
                acc[2] = mfma16(a, u7s[2], acc[2]);
                acc[3] = mfma16(a, u7p[0], acc[3]);
            }
            // issue pass1 streamed kc7 frags (tt 1,3,5) while pass0 cell runs
            #pragma unroll
            for (int i = 0; i < 3; ++i)
                u7s[i] = *(const bf16x8*)(u7base + (size_t)((2 * i + 1) * 64 + l) * 8);

            #pragma unroll
            for (int j = 0; j < 4; ++j) {             // cell, cols w*32 + r
                int row = q * 4 + j;
                float iv = sigm(acc[0][j] + bf2f((unsigned short)gxq[0][j]));
                float fv = sigm(acc[1][j] + bf2f((unsigned short)gxq[1][j]));
                float gv = tanh_f(acc[2][j] + bf2f((unsigned short)gxq[2][j]));
                float ov = sigm(acc[3][j] + bf2f((unsigned short)gxq[3][j]));
                float c = fv * c_st[0][j] + iv * gv;
                c_st[0][j] = c;
                float hv = ov * tanh_f(c);
                int k = w * 32 + r;
                hn[((w * 4 + (r >> 3)) * 16 + row) * 8 + (r & 7)] = f2bf(hv);
                outh[((size_t)(g * 16 + row) * 128 + t) * 256 + k] = hv;
                ypj[j] += hv * fw[0];
            }

            // ================= PASS 1 (sub = 1, tt = gate*2+1) =================
            #pragma unroll
            for (int gate = 0; gate < 4; ++gate) {
                float wv = wy_r[gate * 2 + 1];
                acc[gate][0] = yp[0] * wv; acc[gate][1] = yp[1] * wv;
                acc[gate][2] = yp[2] * wv; acc[gate][3] = yp[3] * wv;
            }
            #pragma unroll
            for (int kcL = 0; kcL < 2; ++kcL) {
                bf16x8 a = *(const bf16x8*)(hp + ((kcL * 4 + q) * 16 + r) * 8);
                #pragma unroll
                for (int gate = 0; gate < 4; ++gate) {
                    bf16x8 b = *(const bf16x8*)(u2 + (size_t)(((w * 2 + kcL) * 8 + gate * 2 + 1) * 64 + l) * 8);
                    acc[gate] = mfma16(a, b, acc[gate]);
                }
            }
            #pragma unroll
            for (int i = 0; i < 5; ++i) {
                bf16x8 a = *(const bf16x8*)(hp + (((2 + i) * 4 + q) * 16 + r) * 8);
                #pragma unroll
                for (int gate = 0; gate < 4; ++gate)
                    acc[gate] = mfma16(a, u_res[i][gate * 2 + 1], acc[gate]);
            }
            {
                bf16x8 a = *(const bf16x8*)(hp + ((7 * 4 + q) * 16 + r) * 8);
                acc[0] = mfma16(a, u7s[0], acc[0]);
                acc[1] = mfma16(a, u7s[1], acc[1]);
                acc[2] = mfma16(a, u7s[2], acc[2]);
                acc[3] = mfma16(a, u7p[1], acc[3]);
            }
            #pragma unroll
            for (int j = 0; j < 4; ++j) {             // cell, cols w*32 + 16 + r
                int row = q * 4 + j;
                float iv = sigm(acc[0][j] + bf2f((unsigned short)gxq[0][4 + j]));
                float fv = sigm(acc[1][j] + bf2f((unsigned short)gxq[1][4 + j]));
                float gv = tanh_f(acc[2][j] + bf2f((unsigned short)gxq[2][4 + j]));
                float ov = sigm(acc[3][j] + bf2f((unsigned short)gxq[3][4 + j]));
                float c = fv * c_st[1][j] + iv * gv;
                c_st[1][j] = c;
                float hv = ov * tanh_f(c);
                int k = w * 32 + 16 + r;
                hn[((w * 4 + 2 + (r >> 3)) * 16 + row) * 8 + (r & 7)] = f2bf(hv);
                outh[((size_t)(g * 16 + row) * 128 + t) * 256 + k] = hv;
                ypj[j] += hv * fw[1];
            }
        }

        #pragma unroll
        for (int j = 0; j < 4; ++j) {   // reduce y partial over the 16-lane group
            float v = ypj[j];
            v += __shfl_xor(v, 1);
            v += __shfl_xor(v, 2);
            v += __shfl_xor(v, 4);
            v += __shfl_xor(v, 8);
            if (r == 0) ypn[w * 16 + q * 4 + j] = v;
        }
        // raw barrier: LDS visibility only; outh stores drain in background.
        asm volatile("s_waitcnt lgkmcnt(0)\n\ts_barrier" ::: "memory");
    }
    if (tid < 16) {
        float y = fc_b0;
        #pragma unroll
        for (int ww = 0; ww < 8; ++ww) y += ypart[ww * 16 + tid];
        out[g * 16 + tid] = y;
    }
}

extern "C" void kernel_launch(void* const* d_in, const int* in_sizes, int n_in,
                              void* d_out, int out_size, void* d_ws, size_t ws_size,
                              hipStream_t stream) {
    const float* H    = (const float*)d_in[0];
    const float* y0   = (const float*)d_in[1];
    const float* Wa   = (const float*)d_in[2];
    // d_in[3] = Ua: multiplied by an all-zero state in the reference -> unused
    const float* ba   = (const float*)d_in[4];
    const float* Va   = (const float*)d_in[5];
    const float* W    = (const float*)d_in[6];
    const float* U    = (const float*)d_in[7];
    const float* bias = (const float*)d_in[8];
    const float* Wy   = (const float*)d_in[9];
    const float* fcW  = (const float*)d_in[10];
    const float* fcb  = (const float*)d_in[11];
    float* out = (float*)d_out;
    char* ws = (char*)d_ws;

    unsigned short* Hbf   = (unsigned short*)(ws);
    unsigned short* HT    = (unsigned short*)(ws + 16777216);
    unsigned short* T1    = (unsigned short*)(ws + 2 * 16777216);
    unsigned short* beta  = (unsigned short*)(ws + 3 * 16777216);
    unsigned short* poolT = (unsigned short*)(ws + 4 * 16777216);
    unsigned short* Gxp   = (unsigned short*)(ws + (size_t)5 * 16777216);        // 134.2 MB
    unsigned short* WaT   = (unsigned short*)(ws + (size_t)5 * 16777216 + 134217728);
    unsigned short* VaT   = WaT + 16384;
    unsigned short* WT    = VaT + 16384;
    unsigned short* Upk   = WT + 131072;

    hipFuncSetAttribute((const void*)k_seq, hipFuncAttributeMaxDynamicSharedMemorySize, 148480);

    hipLaunchKernelGGL(k_prepw, dim3(1664), dim3(256), 0, stream, Wa, Va, W, U, WaT, VaT, WT, Upk);
    hipLaunchKernelGGL(k_preph, dim3(8192), dim3(256), 0, stream, H, Hbf, HT);
    hipLaunchKernelGGL(k_att1, dim3(1024), dim3(256), 0, stream, Hbf, WaT, ba, T1);
    hipLaunchKernelGGL(k_att2, dim3(1024), dim3(256), 0, stream, T1, VaT, beta);
    hipLaunchKernelGGL(k_pool, dim3(1024), dim3(256), 0, stream, beta, HT, poolT);
    hipLaunchKernelGGL(k_gx, dim3(8192), dim3(256), 0, stream, poolT, WT, bias, Gxp);
    hipLaunchKernelGGL(k_seq, dim3(32), dim3(512), 148480, stream, Gxp, Upk, Wy, fcW, fcb, y0, out);
}